// Round 6
// baseline (1870.872 us; speedup 1.0000x reference)
//
#include <hip/hip_runtime.h>

// SNN: T=200, B=256, IN=784, N=1024, OUT=10
// W_rec = -0.5*(ones - I) => prev@W_rec = -0.5*(S_b - prev[b,j])  (exact in
// fp32: all partial sums are multiples of 0.5 with |.| <= 512).
// net_in[t] = x_t @ W_in is time-independent => one big fp32 GEMM up front
// into d_out's hidden_spikes region, then an in-place spike scan.
//
// NUMERICS CONTRACT: dynamics are knife-edge (absmax 512 of 611 = one
// marginal spike-step flip vs BLAS summation order; 2 flips would fail).
// The GEMM keeps a single ascending-k fmaf chain per output element —
// bit-identical across rounds. No MFMA/bf16, no split-K, no reassociation,
// true IEEE division in the scan.
//
// LEARNED (r4/r5): VGPR<=128 hard wall; B-via-global regresses (L1 latency
// not coverable at depth-1); A/B LDS broadcast reads are cheap (4/16-addr) —
// r2's gap is barrier bubbles, so BK=32 halves them. Scan was scatter-bound:
// lane-stride-64B accesses = 64 cache lines per instr; stride-64 lane mapping
// makes every load/store a coalesced 256 B transaction.

#define TT 200
#define BB 256
#define KK 784
#define NN 1024
#define OO 10

#define FMA4(acc, s, v)                                                        \
  acc.x = fmaf(s, v.x, acc.x);                                                 \
  acc.y = fmaf(s, v.y, acc.y);                                                 \
  acc.z = fmaf(s, v.z, acc.z);                                                 \
  acc.w = fmaf(s, v.w, acc.w)

// ---------------- Phase 1: net = X(51200x784) @ W(784x1024), fp32 ----------
// 128x128 tile, BK=32 (24 tiles + 16-k tail), 256 threads, 8x8 micro-tile.
// r2's proven 2-barrier structure, half as many barrier events as BK=16.
__device__ __forceinline__ void fma_step(const float4 (*__restrict__ A4)[32],
                                         const float4 (*__restrict__ B4)[32],
                                         float4 (&acc)[2][2][4], int k, int tx,
                                         int ty) {
  float4 A0 = A4[k][ty];          // 4-addr broadcast (free)
  float4 A1 = A4[k][16 + ty];
  float4 B0 = B4[k][tx];          // 16-addr, 4-way shared (cheap)
  float4 B1 = B4[k][16 + tx];
  FMA4(acc[0][0][0], A0.x, B0);
  FMA4(acc[0][1][0], A0.x, B1);
  FMA4(acc[0][0][1], A0.y, B0);
  FMA4(acc[0][1][1], A0.y, B1);
  FMA4(acc[0][0][2], A0.z, B0);
  FMA4(acc[0][1][2], A0.z, B1);
  FMA4(acc[0][0][3], A0.w, B0);
  FMA4(acc[0][1][3], A0.w, B1);
  FMA4(acc[1][0][0], A1.x, B0);
  FMA4(acc[1][1][0], A1.x, B1);
  FMA4(acc[1][0][1], A1.y, B0);
  FMA4(acc[1][1][1], A1.y, B1);
  FMA4(acc[1][0][2], A1.z, B0);
  FMA4(acc[1][1][2], A1.z, B1);
  FMA4(acc[1][0][3], A1.w, B0);
  FMA4(acc[1][1][3], A1.w, B1);
}

__global__ __launch_bounds__(256)
void gemm_net(const float* __restrict__ X, const float* __restrict__ W,
              float* __restrict__ C) {
  __shared__ float As[32][128];   // [k][m], 16 KB
  __shared__ float Bs[32][128];   // [k][n], 16 KB
  const float4(*As4)[32] = (const float4(*)[32])As;
  const float4(*Bs4)[32] = (const float4(*)[32])Bs;

  const int tid = threadIdx.x;
  const int n0 = blockIdx.x * 128;
  const int m0 = blockIdx.y * 128;
  const int tx = tid & 15;
  const int ty = tid >> 4;
  const int arow = tid >> 1;           // 0..127
  const int ak32 = (tid & 1) * 16;     // 0 or 16 (BK=32 staging)
  const int ak16 = (tid & 1) * 8;      // 0 or 8  (tail staging)
  const int brow = tid >> 5;           // 0..7
  const int bc   = (tid & 31) * 4;     // 0..124

  const float* ap = X + (size_t)(m0 + arow) * KK + ak32;
  const float* bp = W + (size_t)brow * NN + n0 + bc;

  float4 acc[2][2][4] = {};
  float4 a[4], b[4];

  // preload tile 0 (k = 0..31)
#pragma unroll
  for (int i = 0; i < 4; ++i) a[i] = *(const float4*)(ap + 4 * i);
#pragma unroll
  for (int i = 0; i < 4; ++i) b[i] = *(const float4*)(bp + (size_t)(8 * i) * NN);

  for (int t = 0; t < 24; ++t) {
    __syncthreads();                   // previous tile's LDS reads done
#pragma unroll
    for (int i = 0; i < 4; ++i) {      // As write: bank=arow%32, 2-way (free)
      As[ak32 + 4 * i + 0][arow] = a[i].x;
      As[ak32 + 4 * i + 1][arow] = a[i].y;
      As[ak32 + 4 * i + 2][arow] = a[i].z;
      As[ak32 + 4 * i + 3][arow] = a[i].w;
    }
#pragma unroll
    for (int i = 0; i < 4; ++i)        // Bs: lane-consecutive, conflict-free
      *(float4*)&Bs[brow + 8 * i][bc] = b[i];
    __syncthreads();

    if (t < 23) {                      // prefetch next BK=32 tile
      ap += 32;
      bp += 32 * NN;
#pragma unroll
      for (int i = 0; i < 4; ++i) a[i] = *(const float4*)(ap + 4 * i);
#pragma unroll
      for (int i = 0; i < 4; ++i)
        b[i] = *(const float4*)(bp + (size_t)(8 * i) * NN);
    } else {                           // prefetch 16-k tail (k = 768..783)
      const float* apt = X + (size_t)(m0 + arow) * KK + 768 + ak16;
      const float* bpt = W + (size_t)(768 + brow) * NN + n0 + bc;
      a[0] = *(const float4*)(apt);
      a[1] = *(const float4*)(apt + 4);
      b[0] = *(const float4*)(bpt);
      b[1] = *(const float4*)(bpt + (size_t)8 * NN);
    }

#pragma unroll
    for (int k = 0; k < 32; ++k) fma_step(As4, Bs4, acc, k, tx, ty);
  }

  // ---- tail tile, BK=16 ----
  __syncthreads();
  As[ak16 + 0][arow] = a[0].x;
  As[ak16 + 1][arow] = a[0].y;
  As[ak16 + 2][arow] = a[0].z;
  As[ak16 + 3][arow] = a[0].w;
  As[ak16 + 4][arow] = a[1].x;
  As[ak16 + 5][arow] = a[1].y;
  As[ak16 + 6][arow] = a[1].z;
  As[ak16 + 7][arow] = a[1].w;
  *(float4*)&Bs[brow][bc] = b[0];
  *(float4*)&Bs[brow + 8][bc] = b[1];
  __syncthreads();
#pragma unroll
  for (int k = 0; k < 16; ++k) fma_step(As4, Bs4, acc, k, tx, ty);

#pragma unroll
  for (int qi = 0; qi < 2; ++qi)
#pragma unroll
    for (int i = 0; i < 4; ++i) {
      const int r = m0 + qi * 64 + ty * 4 + i;
#pragma unroll
      for (int qj = 0; qj < 2; ++qj)
        *(float4*)(C + (size_t)r * NN + n0 + qj * 64 + tx * 4) =
            acc[qi][qj][i];
    }
}

// ---------------- Phase 2: sequential scan, one WAVE per batch row ---------
// 256 blocks x 64 threads. STRIDE-64 lane mapping: lane L owns neurons
// j = L + 64*i, i=0..15 -> every net load / spike store is a fully
// coalesced 256 B dword access (vs 64-line scatters of r3-r5).
// S via ballot+popcount (exact); spike stores nontemporal (write-once).
__global__ __launch_bounds__(64)
void snn_scan(float* __restrict__ hid, const float* __restrict__ Wout,
              float* __restrict__ logits) {
  constexpr float V_REST = -65.0f, THRESH0 = -50.0f, TAU_M = 20.0f,
                  TAU_TH = 100.0f, BETA = 5.0f, DT = 1.0f;
  const int b = blockIdx.x;
  const int lane = threadIdx.x;
  const size_t base = (size_t)b * NN + lane;   // + i*64
  const size_t STEP = (size_t)BB * NN;

  float mp[16], th[16], prev[16], cnt[16];
#pragma unroll
  for (int i = 0; i < 16; ++i) {
    mp[i] = V_REST; th[i] = THRESH0; prev[i] = 0.0f; cnt[i] = 0.0f;
  }
  float S = 0.0f;

  float nA[16], nB[16];                 // depth-2 net prefetch
#pragma unroll
  for (int i = 0; i < 16; ++i) nA[i] = hid[base + (size_t)i * 64];
#pragma unroll
  for (int i = 0; i < 16; ++i) nB[i] = hid[STEP + base + (size_t)i * 64];

#define SCAN_STEP(t, buf)                                                      \
  {                                                                            \
    float h = -0.5f * S;           /* exact: S integer-valued */               \
    float h5 = h + 0.5f;                                                       \
    int tot = 0;                                                               \
    float sp[16];                                                              \
    _Pragma("unroll") for (int i = 0; i < 16; ++i) {                           \
      float rec = (prev[i] != 0.0f) ? h5 : h; /* = -0.5*(S-prev[i]) exact */   \
      float nv = buf[i] + rec;               /* np elementwise add order */    \
      float m = mp[i] + (V_REST - mp[i]) / TAU_M; /* true IEEE division */     \
      m = m + nv * DT;                                                         \
      bool spk = (m >= th[i]);                                                 \
      float s = spk ? 1.0f : 0.0f;                                             \
      th[i] = (th[i] + BETA * s) - ((th[i] - THRESH0) / TAU_TH) * DT;          \
      mp[i] = spk ? V_REST : m;                                                \
      cnt[i] += s;                                                             \
      prev[i] = s;                                                             \
      sp[i] = s;                                                               \
      tot += __popcll(__ballot(spk));                                          \
    }                                                                          \
    float* out = hid + (size_t)(t)*STEP + base;                                \
    _Pragma("unroll") for (int i = 0; i < 16; ++i)                             \
        __builtin_nontemporal_store(sp[i], out + (size_t)i * 64);              \
    if ((t) + 2 < TT) {                                                        \
      const float* nx = hid + (size_t)((t) + 2) * STEP + base;                 \
      _Pragma("unroll") for (int i = 0; i < 16; ++i)                           \
          buf[i] = nx[(size_t)i * 64];                                         \
    }                                                                          \
    S = (float)tot;                                                            \
  }

  for (int t = 0; t < TT; t += 2) {
    SCAN_STEP(t, nA);
    SCAN_STEP(t + 1, nB);
  }

  // logits[b,o] = sum_j cnt[b,j] * Wout[j,o]   (tiny epilogue)
  float lg[OO];
#pragma unroll
  for (int o = 0; o < OO; ++o) lg[o] = 0.0f;
#pragma unroll
  for (int i = 0; i < 16; ++i) {
    const float* wr = Wout + (size_t)(lane + 64 * i) * OO;
#pragma unroll
    for (int o = 0; o < OO; ++o) lg[o] = fmaf(cnt[i], wr[o], lg[o]);
  }
#pragma unroll
  for (int o = 0; o < OO; ++o) {
    lg[o] += __shfl_xor(lg[o], 1, 64);
    lg[o] += __shfl_xor(lg[o], 2, 64);
    lg[o] += __shfl_xor(lg[o], 4, 64);
    lg[o] += __shfl_xor(lg[o], 8, 64);
    lg[o] += __shfl_xor(lg[o], 16, 64);
    lg[o] += __shfl_xor(lg[o], 32, 64);
  }
  if (lane == 0) {
#pragma unroll
    for (int o = 0; o < OO; ++o) logits[(size_t)b * OO + o] = lg[o];
  }
}

extern "C" void kernel_launch(void* const* d_in, const int* in_sizes, int n_in,
                              void* d_out, int out_size, void* d_ws,
                              size_t ws_size, hipStream_t stream) {
  const float* X    = (const float*)d_in[0];  // input_spikes [200][256][784]
  const float* Win  = (const float*)d_in[1];  // [784][1024]
  // d_in[2] = W_rec — unused (exact closed form)
  const float* Wout = (const float*)d_in[3];  // [1024][10]

  float* logits = (float*)d_out;              // [256][10]
  float* hid    = (float*)d_out + BB * OO;    // [200][256][1024]

  dim3 g1(NN / 128, TT * BB / 128);           // 8 x 400 blocks
  gemm_net<<<g1, 256, 0, stream>>>(X, Win, hid);
  snn_scan<<<BB, 64, 0, stream>>>(hid, Wout, logits);
}

// Round 7
// 1331.873 us; speedup vs baseline: 1.4047x; 1.4047x over previous
//
#include <hip/hip_runtime.h>

// SNN: T=200, B=256, IN=784, N=1024, OUT=10
// W_rec = -0.5*(ones - I) => prev@W_rec = -0.5*(S_b - prev[b,j])  (exact in
// fp32: all partial sums are multiples of 0.5 with |.| <= 512).
// net_in[t] = x_t @ W_in is time-independent => one big fp32 GEMM up front
// into d_out's hidden_spikes region, then an in-place spike scan.
//
// NUMERICS CONTRACT: dynamics are knife-edge (absmax 512 of 611 = one
// marginal whole-row spike-step flip vs BLAS summation order; two flips in
// one row would fail). GEMM keeps a single ascending-k fmaf chain per output
// element — bit-identical to the round-2 passing kernel. No MFMA/bf16 (bf16
// net noise ~0.05 would flip hundreds of row-events), no split-K, true IEEE
// division in the scan.
//
// LEARNED (r4/r6): VGPR > 128 halves occupancy -> ~2x regression; r2's
// BK=16 single-buffer 2-barrier shape at VGPR 52 is the proven optimum.
// LDS broadcasts are bank-free -> DS floor ~80 us, GEMM is issue-bound at
// ~523 us FMA floor; only safe lever left is L2/XCD locality (grid swizzle).
// Scan is load-latency-bound at 1 wave/CU -> deepen prefetch.

#define TT 200
#define BB 256
#define KK 784
#define NN 1024
#define OO 10

#define FMA4(acc, s, v)                                                        \
  acc.x = fmaf(s, v.x, acc.x);                                                 \
  acc.y = fmaf(s, v.y, acc.y);                                                 \
  acc.z = fmaf(s, v.z, acc.z);                                                 \
  acc.w = fmaf(s, v.w, acc.w)

// ---------------- Phase 1: net = X(51200x784) @ W(784x1024), fp32 ----------
// r2's exact structure: 128x128 tile, BK=16, 256 threads, 8x8 micro-tile,
// single LDS buffer, 2 barriers/tile, register prefetch of next tile.
// Grid swapped to (m,n) = (blockIdx.x, blockIdx.y): linear id = m + 400*n,
// id%8 = m%8 -> all 8 n-tiles of an m-strip land on one XCD -> X's 401 KB
// strip is fetched into that XCD's L2 once (FETCH ~660 -> ~250 MB).
__global__ __launch_bounds__(256)
void gemm_net(const float* __restrict__ X, const float* __restrict__ W,
              float* __restrict__ C) {
  __shared__ float As[16][128];   // [k][m] (A staged transposed), 8 KB
  __shared__ float Bs[16][128];   // [k][n], 8 KB
  float4 (*As4)[32] = (float4(*)[32])As;
  float4 (*Bs4)[32] = (float4(*)[32])Bs;

  const int tid = threadIdx.x;
  const int m0 = blockIdx.x * 128;     // m fastest -> same-XCD n-set
  const int n0 = blockIdx.y * 128;
  const int tx = tid & 15;             // cols tx*4, 64+tx*4
  const int ty = tid >> 4;             // rows ty*4, 64+ty*4
  const int arow = tid >> 1;           // 0..127
  const int ak   = (tid & 1) * 8;      // 0 or 8
  const int brow = tid >> 5;           // 0..7 (and +8)
  const int bc   = (tid & 31) * 4;     // 0..124

  const float* ap = X + (size_t)(m0 + arow) * KK + ak;
  const float* bp = W + (size_t)brow * NN + n0 + bc;

  // preload tile 0 into registers
  float4 a0 = *(const float4*)(ap);
  float4 a1 = *(const float4*)(ap + 4);
  float4 b0 = *(const float4*)(bp);
  float4 b1 = *(const float4*)(bp + 8 * NN);

  float4 acc[2][2][4] = {};

  for (int k0 = 0; k0 < KK; k0 += 16) {
    __syncthreads();                   // previous tile's LDS reads done
    As[ak + 0][arow] = a0.x;           // bank=arow%32, 2-way (free)
    As[ak + 1][arow] = a0.y;
    As[ak + 2][arow] = a0.z;
    As[ak + 3][arow] = a0.w;
    As[ak + 4][arow] = a1.x;
    As[ak + 5][arow] = a1.y;
    As[ak + 6][arow] = a1.z;
    As[ak + 7][arow] = a1.w;
    *(float4*)&Bs[brow][bc] = b0;      // lane-consecutive: conflict-free
    *(float4*)&Bs[brow + 8][bc] = b1;
    __syncthreads();

    // prefetch next tile (lands during the ~2048-cyc inner loop)
    if (k0 + 16 < KK) {
      ap += 16;
      bp += 16 * NN;
      a0 = *(const float4*)(ap);
      a1 = *(const float4*)(ap + 4);
      b0 = *(const float4*)(bp);
      b1 = *(const float4*)(bp + 8 * NN);
    }

#pragma unroll
    for (int k = 0; k < 16; ++k) {
      float4 A0 = As4[k][ty];          // broadcast (bank-free)
      float4 A1 = As4[k][16 + ty];
      float4 B0 = Bs4[k][tx];          // 16 unique addrs, 4-way broadcast
      float4 B1 = Bs4[k][16 + tx];
      // one fmaf per acc element per k, ascending k: bit-exact contract
      FMA4(acc[0][0][0], A0.x, B0);
      FMA4(acc[0][1][0], A0.x, B1);
      FMA4(acc[0][0][1], A0.y, B0);
      FMA4(acc[0][1][1], A0.y, B1);
      FMA4(acc[0][0][2], A0.z, B0);
      FMA4(acc[0][1][2], A0.z, B1);
      FMA4(acc[0][0][3], A0.w, B0);
      FMA4(acc[0][1][3], A0.w, B1);
      FMA4(acc[1][0][0], A1.x, B0);
      FMA4(acc[1][1][0], A1.x, B1);
      FMA4(acc[1][0][1], A1.y, B0);
      FMA4(acc[1][1][1], A1.y, B1);
      FMA4(acc[1][0][2], A1.z, B0);
      FMA4(acc[1][1][2], A1.z, B1);
      FMA4(acc[1][0][3], A1.w, B0);
      FMA4(acc[1][1][3], A1.w, B1);
    }
  }

#pragma unroll
  for (int qi = 0; qi < 2; ++qi)
#pragma unroll
    for (int i = 0; i < 4; ++i) {
      const int r = m0 + qi * 64 + ty * 4 + i;
#pragma unroll
      for (int qj = 0; qj < 2; ++qj)
        *(float4*)(C + (size_t)r * NN + n0 + qj * 64 + tx * 4) =
            acc[qi][qj][i];
    }
}

// ---------------- Phase 2: sequential scan, one WAVE per batch row ---------
// 256 blocks x 64 threads. Stride-64 lane mapping: lane L owns neurons
// j = L + 64*i -> every net load / spike store is a coalesced 256 B access.
// S via ballot+popcount (exact integers). Depth-4 net prefetch: loads for
// t+4 issue at step t -> 3-step (~1200 cyc) latency window covers L3/HBM.
__global__ __launch_bounds__(64)
void snn_scan(float* __restrict__ hid, const float* __restrict__ Wout,
              float* __restrict__ logits) {
  constexpr float V_REST = -65.0f, THRESH0 = -50.0f, TAU_M = 20.0f,
                  TAU_TH = 100.0f, BETA = 5.0f, DT = 1.0f;
  const int b = blockIdx.x;
  const int lane = threadIdx.x;
  const size_t base = (size_t)b * NN + lane;   // + i*64
  const size_t STEP = (size_t)BB * NN;

  float mp[16], th[16], prev[16], cnt[16];
#pragma unroll
  for (int i = 0; i < 16; ++i) {
    mp[i] = V_REST; th[i] = THRESH0; prev[i] = 0.0f; cnt[i] = 0.0f;
  }
  float S = 0.0f;

  float buf[4][16];                     // depth-4 net prefetch
#pragma unroll
  for (int d = 0; d < 4; ++d)
#pragma unroll
    for (int i = 0; i < 16; ++i)
      buf[d][i] = hid[(size_t)d * STEP + base + (size_t)i * 64];

#define SCAN_STEP(t, d)                                                        \
  {                                                                            \
    float h = -0.5f * S;           /* exact: S integer-valued */               \
    float h5 = h + 0.5f;                                                       \
    int tot = 0;                                                               \
    float sp[16];                                                              \
    _Pragma("unroll") for (int i = 0; i < 16; ++i) {                           \
      float rec = (prev[i] != 0.0f) ? h5 : h; /* = -0.5*(S-prev[i]) exact */   \
      float nv = buf[d][i] + rec;            /* np elementwise add order */    \
      float m = mp[i] + (V_REST - mp[i]) / TAU_M; /* true IEEE division */     \
      m = m + nv * DT;                                                         \
      bool spk = (m >= th[i]);                                                 \
      float s = spk ? 1.0f : 0.0f;                                             \
      th[i] = (th[i] + BETA * s) - ((th[i] - THRESH0) / TAU_TH) * DT;          \
      mp[i] = spk ? V_REST : m;                                                \
      cnt[i] += s;                                                             \
      prev[i] = s;                                                             \
      sp[i] = s;                                                               \
      tot += __popcll(__ballot(spk));                                          \
    }                                                                          \
    float* out = hid + (size_t)(t)*STEP + base;                                \
    _Pragma("unroll") for (int i = 0; i < 16; ++i)                             \
        __builtin_nontemporal_store(sp[i], out + (size_t)i * 64);              \
    if ((t) + 4 < TT) {                                                        \
      const float* nx = hid + (size_t)((t) + 4) * STEP + base;                 \
      _Pragma("unroll") for (int i = 0; i < 16; ++i)                           \
          buf[d][i] = nx[(size_t)i * 64];                                      \
    }                                                                          \
    S = (float)tot;                                                            \
  }

  for (int t = 0; t < TT; t += 4) {
    SCAN_STEP(t + 0, 0);
    SCAN_STEP(t + 1, 1);
    SCAN_STEP(t + 2, 2);
    SCAN_STEP(t + 3, 3);
  }

  // logits[b,o] = sum_j cnt[b,j] * Wout[j,o]   (tiny epilogue)
  float lg[OO];
#pragma unroll
  for (int o = 0; o < OO; ++o) lg[o] = 0.0f;
#pragma unroll
  for (int i = 0; i < 16; ++i) {
    const float* wr = Wout + (size_t)(lane + 64 * i) * OO;
#pragma unroll
    for (int o = 0; o < OO; ++o) lg[o] = fmaf(cnt[i], wr[o], lg[o]);
  }
#pragma unroll
  for (int o = 0; o < OO; ++o) {
    lg[o] += __shfl_xor(lg[o], 1, 64);
    lg[o] += __shfl_xor(lg[o], 2, 64);
    lg[o] += __shfl_xor(lg[o], 4, 64);
    lg[o] += __shfl_xor(lg[o], 8, 64);
    lg[o] += __shfl_xor(lg[o], 16, 64);
    lg[o] += __shfl_xor(lg[o], 32, 64);
  }
  if (lane == 0) {
#pragma unroll
    for (int o = 0; o < OO; ++o) logits[(size_t)b * OO + o] = lg[o];
  }
}

extern "C" void kernel_launch(void* const* d_in, const int* in_sizes, int n_in,
                              void* d_out, int out_size, void* d_ws,
                              size_t ws_size, hipStream_t stream) {
  const float* X    = (const float*)d_in[0];  // input_spikes [200][256][784]
  const float* Win  = (const float*)d_in[1];  // [784][1024]
  // d_in[2] = W_rec — unused (exact closed form)
  const float* Wout = (const float*)d_in[3];  // [1024][10]

  float* logits = (float*)d_out;              // [256][10]
  float* hid    = (float*)d_out + BB * OO;    // [200][256][1024]

  dim3 g1(TT * BB / 128, NN / 128);           // 400 x 8, m fastest (XCD swz)
  gemm_net<<<g1, 256, 0, stream>>>(X, Win, hid);
  snn_scan<<<BB, 64, 0, stream>>>(hid, Wout, logits);
}

// Round 8
// 1317.375 us; speedup vs baseline: 1.4202x; 1.0110x over previous
//
#include <hip/hip_runtime.h>

// SNN: T=200, B=256, IN=784, N=1024, OUT=10
// W_rec = -0.5*(ones - I) => prev@W_rec = -0.5*(S_b - prev[b,j])  (exact in
// fp32: all partial sums are multiples of 0.5 with |.| <= 512).
// net_in[t] = x_t @ W_in is time-independent => one big fp32 GEMM up front
// into d_out's hidden_spikes region, then an in-place spike scan.
//
// NUMERICS CONTRACT: dynamics are knife-edge (absmax 512 of 611 = one
// marginal whole-row spike-step flip vs BLAS summation order). Each C element
// keeps a single ascending-k IEEE-fma chain — v_pk_fma_f32 packs two
// INDEPENDENT chains per instruction, bit-identical per element. No
// MFMA/bf16, no split-K, true IEEE division in the scan.
//
// LEARNED (r4-r7): VGPR > 128 halves occupancy (~2x regression) — applies to
// BOTH kernels (scan depth-4 spilled, 291->427 us). B-via-global regresses.
// XCD grid swizzle neutral. GEMM is FMA-ISSUE-bound (floor 523 us plain,
// 262 us packed); scan depth-2 stride-64 is its proven optimum (~291 us).

#define TT 200
#define BB 256
#define KK 784
#define NN 1024
#define OO 10

typedef float v2f __attribute__((ext_vector_type(2)));

// two independent packed-fma chains (lo/hi half of a float4 column pair)
#define PK8(accp, s, bl, bh)                                                   \
  accp[0] = __builtin_elementwise_fma((v2f){(s), (s)}, (bl), accp[0]);         \
  accp[1] = __builtin_elementwise_fma((v2f){(s), (s)}, (bh), accp[1])

// ---------------- Phase 1: net = X(51200x784) @ W(784x1024), fp32 ----------
// r2's proven structure: 128x128 tile, BK=16, 256 threads, 8x8 micro-tile,
// single LDS buffer, 2 barriers/tile, register prefetch of next tile.
// Inner loop emits v_pk_fma_f32 (2 fp32 FMA / instr) — GEMM is issue-bound,
// so halving FMA instructions is the one lever that doesn't cost VGPRs.
__global__ __launch_bounds__(256)
void gemm_net(const float* __restrict__ X, const float* __restrict__ W,
              float* __restrict__ C) {
  __shared__ float As[16][128];   // [k][m] (A staged transposed), 8 KB
  __shared__ float Bs[16][128];   // [k][n], 8 KB
  float4 (*As4)[32] = (float4(*)[32])As;
  float4 (*Bs4)[32] = (float4(*)[32])Bs;

  const int tid = threadIdx.x;
  const int m0 = blockIdx.x * 128;
  const int n0 = blockIdx.y * 128;
  const int tx = tid & 15;             // cols tx*4, 64+tx*4
  const int ty = tid >> 4;             // rows ty*4, 64+ty*4
  const int arow = tid >> 1;           // 0..127
  const int ak   = (tid & 1) * 8;      // 0 or 8
  const int brow = tid >> 5;           // 0..7 (and +8)
  const int bc   = (tid & 31) * 4;     // 0..124

  const float* ap = X + (size_t)(m0 + arow) * KK + ak;
  const float* bp = W + (size_t)brow * NN + n0 + bc;

  // preload tile 0 into registers
  float4 a0 = *(const float4*)(ap);
  float4 a1 = *(const float4*)(ap + 4);
  float4 b0 = *(const float4*)(bp);
  float4 b1 = *(const float4*)(bp + 8 * NN);

  // acc[qi][qj][i][lo/hi]: element chains identical to the scalar version
  v2f acc[2][2][4][2] = {};

  for (int k0 = 0; k0 < KK; k0 += 16) {
    __syncthreads();                   // previous tile's LDS reads done
    As[ak + 0][arow] = a0.x;           // bank=arow%32, 2-way (free)
    As[ak + 1][arow] = a0.y;
    As[ak + 2][arow] = a0.z;
    As[ak + 3][arow] = a0.w;
    As[ak + 4][arow] = a1.x;
    As[ak + 5][arow] = a1.y;
    As[ak + 6][arow] = a1.z;
    As[ak + 7][arow] = a1.w;
    *(float4*)&Bs[brow][bc] = b0;      // lane-consecutive: conflict-free
    *(float4*)&Bs[brow + 8][bc] = b1;
    __syncthreads();

    // prefetch next tile (lands during the inner loop)
    if (k0 + 16 < KK) {
      ap += 16;
      bp += 16 * NN;
      a0 = *(const float4*)(ap);
      a1 = *(const float4*)(ap + 4);
      b0 = *(const float4*)(bp);
      b1 = *(const float4*)(bp + 8 * NN);
    }

#pragma unroll
    for (int k = 0; k < 16; ++k) {
      float4 A0 = As4[k][ty];          // broadcast (bank-free)
      float4 A1 = As4[k][16 + ty];
      float4 B0 = Bs4[k][tx];          // 16 unique addrs, 4-way broadcast
      float4 B1 = Bs4[k][16 + tx];
      v2f b0l = {B0.x, B0.y}, b0h = {B0.z, B0.w};
      v2f b1l = {B1.x, B1.y}, b1h = {B1.z, B1.w};
      PK8(acc[0][0][0], A0.x, b0l, b0h);
      PK8(acc[0][1][0], A0.x, b1l, b1h);
      PK8(acc[0][0][1], A0.y, b0l, b0h);
      PK8(acc[0][1][1], A0.y, b1l, b1h);
      PK8(acc[0][0][2], A0.z, b0l, b0h);
      PK8(acc[0][1][2], A0.z, b1l, b1h);
      PK8(acc[0][0][3], A0.w, b0l, b0h);
      PK8(acc[0][1][3], A0.w, b1l, b1h);
      PK8(acc[1][0][0], A1.x, b0l, b0h);
      PK8(acc[1][1][0], A1.x, b1l, b1h);
      PK8(acc[1][0][1], A1.y, b0l, b0h);
      PK8(acc[1][1][1], A1.y, b1l, b1h);
      PK8(acc[1][0][2], A1.z, b0l, b0h);
      PK8(acc[1][1][2], A1.z, b1l, b1h);
      PK8(acc[1][0][3], A1.w, b0l, b0h);
      PK8(acc[1][1][3], A1.w, b1l, b1h);
    }
  }

#pragma unroll
  for (int qi = 0; qi < 2; ++qi)
#pragma unroll
    for (int i = 0; i < 4; ++i) {
      const int r = m0 + qi * 64 + ty * 4 + i;
#pragma unroll
      for (int qj = 0; qj < 2; ++qj) {
        float4 v = {acc[qi][qj][i][0].x, acc[qi][qj][i][0].y,
                    acc[qi][qj][i][1].x, acc[qi][qj][i][1].y};
        *(float4*)(C + (size_t)r * NN + n0 + qj * 64 + tx * 4) = v;
      }
    }
}

// ---------------- Phase 2: sequential scan, one WAVE per batch row ---------
// 256 blocks x 64 threads. Stride-64 lane mapping: lane L owns neurons
// j = L + 64*i -> every net load / spike store is a coalesced 256 B access.
// S via ballot+popcount (exact integers). Depth-2 prefetch (depth-4 spilled).
__global__ __launch_bounds__(64)
void snn_scan(float* __restrict__ hid, const float* __restrict__ Wout,
              float* __restrict__ logits) {
  constexpr float V_REST = -65.0f, THRESH0 = -50.0f, TAU_M = 20.0f,
                  TAU_TH = 100.0f, BETA = 5.0f, DT = 1.0f;
  const int b = blockIdx.x;
  const int lane = threadIdx.x;
  const size_t base = (size_t)b * NN + lane;   // + i*64
  const size_t STEP = (size_t)BB * NN;

  float mp[16], th[16], prev[16], cnt[16];
#pragma unroll
  for (int i = 0; i < 16; ++i) {
    mp[i] = V_REST; th[i] = THRESH0; prev[i] = 0.0f; cnt[i] = 0.0f;
  }
  float S = 0.0f;

  float nA[16], nB[16];                 // depth-2 net prefetch
#pragma unroll
  for (int i = 0; i < 16; ++i) nA[i] = hid[base + (size_t)i * 64];
#pragma unroll
  for (int i = 0; i < 16; ++i) nB[i] = hid[STEP + base + (size_t)i * 64];

#define SCAN_STEP(t, buf)                                                      \
  {                                                                            \
    float h = -0.5f * S;           /* exact: S integer-valued */               \
    float h5 = h + 0.5f;                                                       \
    int tot = 0;                                                               \
    float sp[16];                                                              \
    _Pragma("unroll") for (int i = 0; i < 16; ++i) {                           \
      float rec = (prev[i] != 0.0f) ? h5 : h; /* = -0.5*(S-prev[i]) exact */   \
      float nv = buf[i] + rec;               /* np elementwise add order */    \
      float m = mp[i] + (V_REST - mp[i]) / TAU_M; /* true IEEE division */     \
      m = m + nv * DT;                                                         \
      bool spk = (m >= th[i]);                                                 \
      float s = spk ? 1.0f : 0.0f;                                             \
      th[i] = (th[i] + BETA * s) - ((th[i] - THRESH0) / TAU_TH) * DT;          \
      mp[i] = spk ? V_REST : m;                                                \
      cnt[i] += s;                                                             \
      prev[i] = s;                                                             \
      sp[i] = s;                                                               \
      tot += __popcll(__ballot(spk));                                          \
    }                                                                          \
    float* out = hid + (size_t)(t)*STEP + base;                                \
    _Pragma("unroll") for (int i = 0; i < 16; ++i)                             \
        __builtin_nontemporal_store(sp[i], out + (size_t)i * 64);              \
    if ((t) + 2 < TT) {                                                        \
      const float* nx = hid + (size_t)((t) + 2) * STEP + base;                 \
      _Pragma("unroll") for (int i = 0; i < 16; ++i)                           \
          buf[i] = nx[(size_t)i * 64];                                         \
    }                                                                          \
    S = (float)tot;                                                            \
  }

  for (int t = 0; t < TT; t += 2) {
    SCAN_STEP(t, nA);
    SCAN_STEP(t + 1, nB);
  }

  // logits[b,o] = sum_j cnt[b,j] * Wout[j,o]   (tiny epilogue)
  float lg[OO];
#pragma unroll
  for (int o = 0; o < OO; ++o) lg[o] = 0.0f;
#pragma unroll
  for (int i = 0; i < 16; ++i) {
    const float* wr = Wout + (size_t)(lane + 64 * i) * OO;
#pragma unroll
    for (int o = 0; o < OO; ++o) lg[o] = fmaf(cnt[i], wr[o], lg[o]);
  }
#pragma unroll
  for (int o = 0; o < OO; ++o) {
    lg[o] += __shfl_xor(lg[o], 1, 64);
    lg[o] += __shfl_xor(lg[o], 2, 64);
    lg[o] += __shfl_xor(lg[o], 4, 64);
    lg[o] += __shfl_xor(lg[o], 8, 64);
    lg[o] += __shfl_xor(lg[o], 16, 64);
    lg[o] += __shfl_xor(lg[o], 32, 64);
  }
  if (lane == 0) {
#pragma unroll
    for (int o = 0; o < OO; ++o) logits[(size_t)b * OO + o] = lg[o];
  }
}

extern "C" void kernel_launch(void* const* d_in, const int* in_sizes, int n_in,
                              void* d_out, int out_size, void* d_ws,
                              size_t ws_size, hipStream_t stream) {
  const float* X    = (const float*)d_in[0];  // input_spikes [200][256][784]
  const float* Win  = (const float*)d_in[1];  // [784][1024]
  // d_in[2] = W_rec — unused (exact closed form)
  const float* Wout = (const float*)d_in[3];  // [1024][10]

  float* logits = (float*)d_out;              // [256][10]
  float* hid    = (float*)d_out + BB * OO;    // [200][256][1024]

  dim3 g1(TT * BB / 128, NN / 128);           // 400 x 8 blocks
  gemm_net<<<g1, 256, 0, stream>>>(X, Win, hid);
  snn_scan<<<BB, 64, 0, stream>>>(hid, Wout, logits);
}